// Round 1
// baseline (246.255 us; speedup 1.0000x reference)
//
#include <hip/hip_runtime.h>
#include <hip/hip_bf16.h>

#define C_DIM 100000
#define NROW 512
#define DDIM 512
#define BN 64
#define BK 32
#define BSTR 40   // padded LDS row stride (bf16 elems): 80B = 16B-aligned, bank-step 20

typedef __attribute__((ext_vector_type(4))) float f32x4;
typedef __attribute__((ext_vector_type(2))) float f32x2;
typedef __attribute__((ext_vector_type(8))) short bf16x8;
typedef __attribute__((ext_vector_type(4))) float f32acc;

// ---------------- kernel 1: inv row norms of W (norm over C per row d) ----------
__global__ __launch_bounds__(256) void cf_knorm(const float* __restrict__ W,
                                                float* __restrict__ inv_norm) {
    const int d = blockIdx.x;
    const float* row = W + (size_t)d * C_DIM;
    float s = 0.f;
    for (int c4 = threadIdx.x; c4 < C_DIM / 4; c4 += 256) {
        f32x4 v = *(const f32x4*)(row + c4 * 4);
        s += v.x * v.x + v.y * v.y + v.z * v.z + v.w * v.w;
    }
    #pragma unroll
    for (int off = 32; off; off >>= 1) s += __shfl_down(s, off, 64);
    __shared__ float wsum[4];
    if ((threadIdx.x & 63) == 0) wsum[threadIdx.x >> 6] = s;
    __syncthreads();
    if (threadIdx.x == 0) {
        float t = wsum[0] + wsum[1] + wsum[2] + wsum[3];
        inv_norm[d] = 1.0f / sqrtf(t);
    }
}

// ---------------- kernel 2: xs = bf16(x * inv_norm[d]) --------------------------
__global__ __launch_bounds__(256) void cf_kxs(const float* __restrict__ x,
                                              const float* __restrict__ inv_norm,
                                              __hip_bfloat16* __restrict__ xs) {
    int idx = blockIdx.x * 256 + threadIdx.x;   // 0..262143
    int d = idx & (DDIM - 1);
    xs[idx] = __float2bfloat16(x[idx] * inv_norm[d]);
}

// ---------------- kernel 3: target logits, cos_m, final -------------------------
__global__ __launch_bounds__(64) void cf_ktgt(const float* __restrict__ x,
                                              const float* __restrict__ W,
                                              const float* __restrict__ inv_norm,
                                              const int* __restrict__ label,
                                              float* __restrict__ tl,
                                              float* __restrict__ cm,
                                              float* __restrict__ fl) {
    const int i = blockIdx.x;
    const int lane = threadIdx.x;
    const int lab = label[i];
    float s = 0.f;
    for (int d = lane; d < DDIM; d += 64)
        s += x[(size_t)i * DDIM + d] * inv_norm[d] * W[(size_t)d * C_DIM + lab];
    #pragma unroll
    for (int off = 32; off; off >>= 1) s += __shfl_down(s, off, 64);
    if (lane == 0) {
        float t = fminf(fmaxf(s, -1.f), 1.f);
        float sn = sqrtf(fmaxf(1.f - t * t, 0.f));
        float c = t * 0.8775825618903728f - sn * 0.479425538604203f; // cos(th+m)
        tl[i] = t;
        cm[i] = c;
        fl[i] = (t > -0.8775825618903728f) ? c : (t - 0.2397127693021015f);
    }
}

// ---------------- kernel 4: t = 0.01 * mean(target_logit) -----------------------
__global__ __launch_bounds__(512) void cf_kt(const float* __restrict__ tl,
                                             float* __restrict__ tout) {
    float s = tl[threadIdx.x];
    #pragma unroll
    for (int off = 32; off; off >>= 1) s += __shfl_down(s, off, 64);
    __shared__ float w[8];
    if ((threadIdx.x & 63) == 0) w[threadIdx.x >> 6] = s;
    __syncthreads();
    if (threadIdx.x == 0) {
        float tt = 0.f;
        #pragma unroll
        for (int j = 0; j < 8; ++j) tt += w[j];
        tout[0] = 0.01f * (tt / 512.0f);
    }
}

// ---------------- kernel 5: GEMM (bf16 MFMA) + fused epilogue -------------------
// BM=512 (all rows, W read once), BN=64, BK=32. 512 thr = 8 waves, each wave owns
// a 64x64 output tile. A-frags straight from L2-hot xs (k-contiguous). B staged
// to LDS transposed [c][k] (stride 40 -> conflict-light), double-buffered.
__global__ __launch_bounds__(512, 4) void cf_kgemm(
    const __hip_bfloat16* __restrict__ xs,
    const float* __restrict__ W,
    const int* __restrict__ label,
    const float* __restrict__ cosm,
    const float* __restrict__ finl,
    const float* __restrict__ tp,
    float* __restrict__ out) {
    __shared__ __attribute__((aligned(16))) __hip_bfloat16 Bl[2][BN][BSTR];

    const int tid  = threadIdx.x;
    const int wv   = tid >> 6;       // 0..7  -> row block wv*64
    const int lane = tid & 63;
    const int cb   = blockIdx.x * BN;

    // staging decomposition: thread covers 2 k-rows x 2 cols
    const int k2 = tid >> 5;          // 0..15 -> k = 2*k2, 2*k2+1
    const int c0 = (tid & 31) * 2;    // 0..62

    f32acc acc[4][4];
    #pragma unroll
    for (int m = 0; m < 4; ++m)
        #pragma unroll
        for (int n = 0; n < 4; ++n)
            acc[m][n] = (f32acc){0.f, 0.f, 0.f, 0.f};

    auto stage = [&](int buf, int kt) {
        const int kb = kt * BK;
        const int gc = cb + c0;
        f32x2 v0; v0.x = 0.f; v0.y = 0.f;
        f32x2 v1; v1.x = 0.f; v1.y = 0.f;
        if (gc < C_DIM) {
            v0 = *(const f32x2*)(W + (size_t)(kb + 2 * k2) * C_DIM + gc);
            v1 = *(const f32x2*)(W + (size_t)(kb + 2 * k2 + 1) * C_DIM + gc);
        }
        union { __hip_bfloat16 h[2]; unsigned u; } p0, p1;
        p0.h[0] = __float2bfloat16(v0.x); p0.h[1] = __float2bfloat16(v1.x);
        p1.h[0] = __float2bfloat16(v0.y); p1.h[1] = __float2bfloat16(v1.y);
        *(unsigned*)&Bl[buf][c0][2 * k2]     = p0.u;
        *(unsigned*)&Bl[buf][c0 + 1][2 * k2] = p1.u;
    };

    stage(0, 0);
    __syncthreads();

    int buf = 0;
    const int khalf = (lane >> 4) * 8;   // k-offset of this lane's fragment chunk
    #pragma unroll 1
    for (int kt = 0; kt < DDIM / BK; ++kt) {
        if (kt + 1 < DDIM / BK) stage(buf ^ 1, kt + 1);

        bf16x8 a[4], b[4];
        const int kb = kt * BK + khalf;
        #pragma unroll
        for (int m = 0; m < 4; ++m) {
            const int r = wv * 64 + m * 16 + (lane & 15);
            a[m] = *(const bf16x8*)(xs + (size_t)r * DDIM + kb);
        }
        #pragma unroll
        for (int n = 0; n < 4; ++n) {
            const int c = n * 16 + (lane & 15);
            b[n] = *(const bf16x8*)&Bl[buf][c][khalf];
        }
        #pragma unroll
        for (int m = 0; m < 4; ++m)
            #pragma unroll
            for (int n = 0; n < 4; ++n)
                acc[m][n] = __builtin_amdgcn_mfma_f32_16x16x32_bf16(a[m], b[n], acc[m][n], 0, 0, 0);

        __syncthreads();
        buf ^= 1;
    }

    // fused epilogue
    const float t = tp[0];
    #pragma unroll
    for (int m = 0; m < 4; ++m) {
        const int rbase = wv * 64 + m * 16 + ((lane >> 4) << 2);
        #pragma unroll
        for (int r4 = 0; r4 < 4; ++r4) {
            const int i = rbase + r4;
            const float cmv = cosm[i];
            const float flv = finl[i];
            const int lab = label[i];
            #pragma unroll
            for (int n = 0; n < 4; ++n) {
                const int c = cb + n * 16 + (lane & 15);
                float v = acc[m][n][r4];
                float cz = fminf(fmaxf(v, -1.f), 1.f);
                float o = (cz > cmv) ? cz * (t + cz) : cz;
                if (c == lab) o = flv;
                if (c < C_DIM) out[(size_t)i * C_DIM + c] = o * 64.0f;
            }
        }
    }
}

extern "C" void kernel_launch(void* const* d_in, const int* in_sizes, int n_in,
                              void* d_out, int out_size, void* d_ws, size_t ws_size,
                              hipStream_t stream) {
    const float* x   = (const float*)d_in[0];
    const float* W   = (const float*)d_in[1];
    const int* label = (const int*)d_in[2];
    float* out = (float*)d_out;

    char* ws = (char*)d_ws;
    float* inv_norm = (float*)ws;          // 512 f32
    float* tl  = inv_norm + 512;
    float* cm  = tl + 512;
    float* fl  = cm + 512;
    float* tsc = fl + 512;
    __hip_bfloat16* xs = (__hip_bfloat16*)(ws + 16384);  // 512*512 bf16 = 512KB

    cf_knorm<<<DDIM, 256, 0, stream>>>(W, inv_norm);
    cf_kxs<<<(NROW * DDIM) / 256, 256, 0, stream>>>(x, inv_norm, xs);
    cf_ktgt<<<NROW, 64, 0, stream>>>(x, W, inv_norm, label, tl, cm, fl);
    cf_kt<<<1, 512, 0, stream>>>(tl, tsc);

    const int nblk = (C_DIM + BN - 1) / BN;   // 1563
    cf_kgemm<<<nblk, 512, 0, stream>>>(xs, W, label, cm, fl, tsc, out);
}